// Round 1
// baseline (4667.072 us; speedup 1.0000x reference)
//
#include <hip/hip_runtime.h>
#include <hip/hip_bf16.h>
#include <math.h>

#define N_NODES 50000
#define N_EDGES 640000
#define HDIM    128
#define D_OUT   64
#define G_GRAPHS 500
#define EPSV    1e-5f

// ---------------------------------------------------------------------------
// Degree computation
// ---------------------------------------------------------------------------
__global__ void count_deg_kernel(const int* __restrict__ dst, int* __restrict__ cnt, int E) {
    int i = blockIdx.x * blockDim.x + threadIdx.x;
    if (i < E) atomicAdd(&cnt[dst[i]], 1);
}

__global__ void finalize_deg_kernel(const int* __restrict__ cnt,
                                    float* __restrict__ dinv,
                                    float* __restrict__ rdegn, int n) {
    int i = blockIdx.x * blockDim.x + threadIdx.x;
    if (i < n) {
        float c = (float)cnt[i];
        dinv[i]  = rsqrtf(c + 1.0f);          // GCN deg includes self-loop
        rdegn[i] = 1.0f / fmaxf(c, 1.0f);     // SAGE mean denominator
    }
}

// ---------------------------------------------------------------------------
// GEMM: C[n][128] = A[n][128] @ W[128][128] (+bias) (+accumulate) (row-scaled A)
// Block: 256 threads, 64 rows x 128 cols per block, BK=32 staged in LDS.
// ---------------------------------------------------------------------------
__global__ __launch_bounds__(256) void gemm_h128(
    const float* __restrict__ A, const float* __restrict__ W,
    float* __restrict__ C, const float* __restrict__ bias,
    const float* __restrict__ rowScale, int nrows, int accum)
{
    __shared__ float a_s[64][32];
    __shared__ float w_s[32][128];
    const int tid = threadIdx.x;
    const int tx  = tid & 31;   // column group: cols tx*4..tx*4+3
    const int ty  = tid >> 5;   // row group: rows ty*8..ty*8+7
    const int row0 = blockIdx.x * 64;

    float acc[8][4];
    #pragma unroll
    for (int i = 0; i < 8; i++)
        #pragma unroll
        for (int j = 0; j < 4; j++) acc[i][j] = 0.f;

    for (int kc = 0; kc < 128; kc += 32) {
        // stage A chunk: 64 rows x 32 cols = 512 float4
        #pragma unroll
        for (int s = 0; s < 2; s++) {
            int q  = tid + s * 256;
            int r  = q >> 3;
            int c4 = (q & 7) * 4;
            int row = row0 + r;
            float4 v = make_float4(0.f, 0.f, 0.f, 0.f);
            if (row < nrows) {
                v = *(const float4*)&A[(size_t)row * 128 + kc + c4];
                if (rowScale) {
                    float sc = rowScale[row];
                    v.x *= sc; v.y *= sc; v.z *= sc; v.w *= sc;
                }
            }
            *(float4*)&a_s[r][c4] = v;
        }
        // stage W chunk: 32 rows x 128 cols = 1024 float4
        #pragma unroll
        for (int s = 0; s < 4; s++) {
            int q  = tid + s * 256;
            int r  = q >> 5;
            int c4 = (q & 31) * 4;
            *(float4*)&w_s[r][c4] = *(const float4*)&W[(size_t)(kc + r) * 128 + c4];
        }
        __syncthreads();
        #pragma unroll
        for (int k = 0; k < 32; k++) {
            float4 w4 = *(float4*)&w_s[k][tx * 4];
            #pragma unroll
            for (int i = 0; i < 8; i++) {
                float a = a_s[ty * 8 + i][k];
                acc[i][0] = fmaf(a, w4.x, acc[i][0]);
                acc[i][1] = fmaf(a, w4.y, acc[i][1]);
                acc[i][2] = fmaf(a, w4.z, acc[i][2]);
                acc[i][3] = fmaf(a, w4.w, acc[i][3]);
            }
        }
        __syncthreads();
    }

    float4 bv = make_float4(0.f, 0.f, 0.f, 0.f);
    if (bias) bv = *(const float4*)&bias[tx * 4];
    #pragma unroll
    for (int i = 0; i < 8; i++) {
        int row = row0 + ty * 8 + i;
        if (row >= nrows) continue;
        float4 o;
        o.x = acc[i][0] + bv.x;
        o.y = acc[i][1] + bv.y;
        o.z = acc[i][2] + bv.z;
        o.w = acc[i][3] + bv.w;
        float* cp = &C[(size_t)row * 128 + tx * 4];
        if (accum) {
            float4 c = *(float4*)cp;
            o.x += c.x; o.y += c.y; o.z += c.z; o.w += c.w;
        }
        *(float4*)cp = o;
    }
}

// ---------------------------------------------------------------------------
// GCN: agg init (bias + self-loop term), then edge scatter with sym norm
// ---------------------------------------------------------------------------
__global__ void agg_init_kernel(const float* __restrict__ hw,
                                const float* __restrict__ dinv,
                                const float* __restrict__ gcn_b,
                                float* __restrict__ agg, int n)
{
    int t = blockIdx.x * blockDim.x + threadIdx.x;
    int row = t >> 5;
    int c4  = (t & 31) * 4;
    if (row >= n) return;
    float di = dinv[row];
    float sl = di * di;
    float4 v = *(const float4*)&hw[(size_t)row * 128 + c4];
    float4 b = *(const float4*)&gcn_b[c4];
    float4 o = make_float4(b.x + v.x * sl, b.y + v.y * sl,
                           b.z + v.z * sl, b.w + v.w * sl);
    *(float4*)&agg[(size_t)row * 128 + c4] = o;
}

__global__ void gcn_scatter_kernel(const float* __restrict__ hw,
                                   const int* __restrict__ src,
                                   const int* __restrict__ dst,
                                   const float* __restrict__ dinv,
                                   float* __restrict__ agg, int E)
{
    int t = blockIdx.x * blockDim.x + threadIdx.x;
    int e  = t >> 5;
    int c4 = (t & 31) * 4;
    if (e >= E) return;
    int s = src[e], d = dst[e];
    float nrm = dinv[s] * dinv[d];
    float4 v = *(const float4*)&hw[(size_t)s * 128 + c4];
    float* ap = &agg[(size_t)d * 128 + c4];
    atomicAdd(ap + 0, v.x * nrm);
    atomicAdd(ap + 1, v.y * nrm);
    atomicAdd(ap + 2, v.z * nrm);
    atomicAdd(ap + 3, v.w * nrm);
}

__global__ void sage_scatter_kernel(const float* __restrict__ h,
                                    const int* __restrict__ src,
                                    const int* __restrict__ dst,
                                    float* __restrict__ msum, int E)
{
    int t = blockIdx.x * blockDim.x + threadIdx.x;
    int e  = t >> 5;
    int c4 = (t & 31) * 4;
    if (e >= E) return;
    int s = src[e], d = dst[e];
    float4 v = *(const float4*)&h[(size_t)s * 128 + c4];
    float* mp = &msum[(size_t)d * 128 + c4];
    atomicAdd(mp + 0, v.x);
    atomicAdd(mp + 1, v.y);
    atomicAdd(mp + 2, v.z);
    atomicAdd(mp + 3, v.w);
}

// ---------------------------------------------------------------------------
// Fused: conv blend -> LayerNorm blend -> activation blend -> skip accumulate
// One 64-lane wave per row (lane owns channels c and c+64).
// ---------------------------------------------------------------------------
__global__ __launch_bounds__(256) void fuse_combine_kernel(
    const float* __restrict__ agg, const float* __restrict__ hs,
    const float* __restrict__ aconv, const float* __restrict__ anorm,
    const float* __restrict__ aact,
    const float* __restrict__ lng, const float* __restrict__ lnb,
    float* __restrict__ h, float* __restrict__ skip, int first, int n)
{
    int wave = threadIdx.x >> 6;
    int lane = threadIdx.x & 63;
    int row = blockIdx.x * 4 + wave;
    if (row >= n) return;

    // softmax over architecture params (tiny, recomputed per thread)
    float c0 = aconv[0], c1 = aconv[1];
    float m = fmaxf(c0, c1);
    float e0 = expf(c0 - m), e1 = expf(c1 - m);
    float wc0 = e0 / (e0 + e1), wc1 = e1 / (e0 + e1);

    float q0 = anorm[0], q1 = anorm[1];
    m = fmaxf(q0, q1);
    e0 = expf(q0 - m); e1 = expf(q1 - m);
    float wn0 = e0 / (e0 + e1), wn1 = e1 / (e0 + e1);

    float a0 = aact[0], a1 = aact[1], a2 = aact[2];
    m = fmaxf(fmaxf(a0, a1), a2);
    float f0 = expf(a0 - m), f1 = expf(a1 - m), f2 = expf(a2 - m);
    float fs = f0 + f1 + f2;
    float wa0 = f0 / fs, wa1 = f1 / fs, wa2 = f2 / fs;

    size_t base = (size_t)row * 128;
    int cA = lane, cB = lane + 64;
    float t0 = wc0 * agg[base + cA] + wc1 * hs[base + cA];
    float t1 = wc0 * agg[base + cB] + wc1 * hs[base + cB];

    float s  = t0 + t1;
    float s2 = t0 * t0 + t1 * t1;
    #pragma unroll
    for (int o = 32; o; o >>= 1) {
        s  += __shfl_xor(s, o);
        s2 += __shfl_xor(s2, o);
    }
    float mu   = s * (1.f / 128.f);
    float var  = s2 * (1.f / 128.f) - mu * mu;
    float rstd = rsqrtf(var + EPSV);

    #pragma unroll
    for (int half = 0; half < 2; half++) {
        int c   = half ? cB : cA;
        float t = half ? t1 : t0;
        float ln = (t - mu) * rstd * lng[c] + lnb[c];
        float hv = wn0 * ln + wn1 * t;
        float rl = fmaxf(hv, 0.f);
        float th = tanhf(hv);
        float el = hv > 0.f ? hv : expm1f(hv);
        float out = wa0 * rl + wa1 * th + wa2 * el;
        h[base + c] = out;
        if (first) skip[base + c] = out;
        else       skip[base + c] += out;
    }
}

// ---------------------------------------------------------------------------
// Pooling: batch is sorted -> run-length accumulate in registers, few atomics
// Block: 256 threads; thread owns channel (tid&127), walks 32 nodes.
// ---------------------------------------------------------------------------
__global__ __launch_bounds__(256) void pool_sum_kernel(
    const float* __restrict__ skip, const int* __restrict__ batch,
    float* __restrict__ pooled, int n)
{
    int c   = threadIdx.x & 127;
    int seg = threadIdx.x >> 7;
    int n0  = blockIdx.x * 64 + seg * 32;
    int g_cur = -1;
    float acc = 0.f;
    for (int i = 0; i < 32; i++) {
        int node = n0 + i;
        if (node >= n) break;
        int g = batch[node];
        if (g != g_cur) {
            if (g_cur >= 0) atomicAdd(&pooled[(size_t)g_cur * 128 + c], acc);
            g_cur = g; acc = 0.f;
        }
        acc += skip[(size_t)node * 128 + c];
    }
    if (g_cur >= 0) atomicAdd(&pooled[(size_t)g_cur * 128 + c], acc);
}

// ---------------------------------------------------------------------------
// Final tiny GEMM: out[500][64] = pooled[500][128] @ post_w[128][64] + post_b
// ---------------------------------------------------------------------------
__global__ __launch_bounds__(64) void post_gemm_kernel(
    const float* __restrict__ pooled, const float* __restrict__ W,
    const float* __restrict__ b, float* __restrict__ out)
{
    __shared__ float p_s[128];
    int g = blockIdx.x;
    int j = threadIdx.x;
    p_s[j]      = pooled[(size_t)g * 128 + j];
    p_s[j + 64] = pooled[(size_t)g * 128 + 64 + j];
    __syncthreads();
    float acc = b[j];
    #pragma unroll
    for (int k = 0; k < 128; k++)
        acc = fmaf(p_s[k], W[k * 64 + j], acc);
    out[(size_t)g * 64 + j] = acc;
}

// ---------------------------------------------------------------------------
extern "C" void kernel_launch(void* const* d_in, const int* in_sizes, int n_in,
                              void* d_out, int out_size, void* d_ws, size_t ws_size,
                              hipStream_t stream)
{
    const float* x       = (const float*)d_in[0];
    const int*   ei      = (const int*)d_in[1];
    const int*   batch   = (const int*)d_in[2];
    const float* pre_w   = (const float*)d_in[3];
    const float* pre_b   = (const float*)d_in[4];
    const float* post_w  = (const float*)d_in[5];
    const float* post_b  = (const float*)d_in[6];
    const float* gcn_w   = (const float*)d_in[7];
    const float* gcn_b   = (const float*)d_in[8];
    const float* sage_ws = (const float*)d_in[9];
    const float* sage_wn = (const float*)d_in[10];
    const float* ln_g    = (const float*)d_in[11];
    const float* ln_b    = (const float*)d_in[12];
    const float* a_conv  = (const float*)d_in[13];
    const float* a_norm  = (const float*)d_in[14];
    const float* a_act   = (const float*)d_in[15];

    const int* src = ei;
    const int* dst = ei + N_EDGES;

    // workspace layout
    char* w = (char*)d_ws;
    const size_t NH = (size_t)N_NODES * 128 * sizeof(float);   // 25.6 MB
    float* h     = (float*)(w);
    float* bufB  = (float*)(w + NH);        // hw (GCN) then msum (SAGE)
    float* agg   = (float*)(w + 2 * NH);
    float* hs    = (float*)(w + 3 * NH);
    float* skip  = (float*)(w + 4 * NH);
    float* dinv  = (float*)(w + 5 * NH);
    float* rdegn = dinv + N_NODES;
    int*   cnt   = (int*)(rdegn + N_NODES);
    float* pooled= (float*)(cnt + N_NODES);

    const int GEMM_BLOCKS = (N_NODES + 63) / 64;

    // degrees
    hipMemsetAsync(cnt, 0, N_NODES * sizeof(int), stream);
    count_deg_kernel<<<(N_EDGES + 255) / 256, 256, 0, stream>>>(dst, cnt, N_EDGES);
    finalize_deg_kernel<<<(N_NODES + 255) / 256, 256, 0, stream>>>(cnt, dinv, rdegn, N_NODES);

    // pre-MLP
    gemm_h128<<<GEMM_BLOCKS, 256, 0, stream>>>(x, pre_w, h, pre_b, nullptr, N_NODES, 0);

    for (int l = 0; l < 2; l++) {
        // GCN branch: hw = h @ gcn_w[l]; agg = bias + selfloop + scatter
        gemm_h128<<<GEMM_BLOCKS, 256, 0, stream>>>(h, gcn_w + (size_t)l * 128 * 128,
                                                   bufB, nullptr, nullptr, N_NODES, 0);
        agg_init_kernel<<<((size_t)N_NODES * 32 + 255) / 256, 256, 0, stream>>>(
            bufB, dinv, gcn_b + l * 128, agg, N_NODES);
        gcn_scatter_kernel<<<((size_t)N_EDGES * 32 + 255) / 256, 256, 0, stream>>>(
            bufB, src, dst, dinv, agg, N_EDGES);

        // SAGE branch: hs = h @ sage_ws[l]; msum scatter; hs += mean @ sage_wn[l]
        gemm_h128<<<GEMM_BLOCKS, 256, 0, stream>>>(h, sage_ws + (size_t)l * 128 * 128,
                                                   hs, nullptr, nullptr, N_NODES, 0);
        hipMemsetAsync(bufB, 0, NH, stream);
        sage_scatter_kernel<<<((size_t)N_EDGES * 32 + 255) / 256, 256, 0, stream>>>(
            h, src, dst, bufB, N_EDGES);
        gemm_h128<<<GEMM_BLOCKS, 256, 0, stream>>>(bufB, sage_wn + (size_t)l * 128 * 128,
                                                   hs, nullptr, rdegn, N_NODES, 1);

        // combine + LayerNorm blend + activation blend + skip
        fuse_combine_kernel<<<(N_NODES + 3) / 4, 256, 0, stream>>>(
            agg, hs, a_conv + l * 2, a_norm + l * 2, a_act + l * 3,
            ln_g + l * 128, ln_b + l * 128, h, skip, (l == 0) ? 1 : 0, N_NODES);
    }

    // pooling + post-MLP
    hipMemsetAsync(pooled, 0, (size_t)G_GRAPHS * 128 * sizeof(float), stream);
    pool_sum_kernel<<<(N_NODES + 63) / 64, 256, 0, stream>>>(skip, batch, pooled, N_NODES);
    post_gemm_kernel<<<G_GRAPHS, 64, 0, stream>>>(pooled, post_w, post_b, (float*)d_out);
}

// Round 2
// 590.815 us; speedup vs baseline: 7.8994x; 7.8994x over previous
//
#include <hip/hip_runtime.h>
#include <hip/hip_bf16.h>
#include <math.h>

#define N_NODES 50000
#define N_EDGES 640000
#define HDIM    128
#define D_OUT   64
#define G_GRAPHS 500
#define EPSV    1e-5f

// ---------------------------------------------------------------------------
// Degree computation
// ---------------------------------------------------------------------------
__global__ void count_deg_kernel(const int* __restrict__ dst, int* __restrict__ cnt, int E) {
    int i = blockIdx.x * blockDim.x + threadIdx.x;
    if (i < E) atomicAdd(&cnt[dst[i]], 1);
}

__global__ void finalize_deg_kernel(const int* __restrict__ cnt,
                                    float* __restrict__ dinv,
                                    float* __restrict__ rdegn, int n) {
    int i = blockIdx.x * blockDim.x + threadIdx.x;
    if (i < n) {
        float c = (float)cnt[i];
        dinv[i]  = rsqrtf(c + 1.0f);          // GCN deg includes self-loop
        rdegn[i] = 1.0f / fmaxf(c, 1.0f);     // SAGE mean denominator
    }
}

// ---------------------------------------------------------------------------
// Exclusive scan of cnt[0..n) -> ofs[0..n], also duplicated into cursor.
// Single block of 1024 threads, wave-level shfl scan + cross-wave LDS scan.
// ---------------------------------------------------------------------------
__global__ __launch_bounds__(1024) void scan_offsets_kernel(
    const int* __restrict__ cnt, int* __restrict__ ofs,
    int* __restrict__ cursor, int n)
{
    __shared__ int wsum[16];
    __shared__ int running_s;
    const int tid  = threadIdx.x;
    const int lane = tid & 63;
    const int wid  = tid >> 6;
    if (tid == 0) running_s = 0;
    __syncthreads();

    for (int base = 0; base < n; base += 1024) {
        int i = base + tid;
        int v = (i < n) ? cnt[i] : 0;
        // inclusive wave scan
        int x = v;
        #pragma unroll
        for (int o = 1; o < 64; o <<= 1) {
            int t = __shfl_up(x, o);
            if (lane >= o) x += t;
        }
        if (lane == 63) wsum[wid] = x;
        __syncthreads();
        if (wid == 0) {
            int y = (lane < 16) ? wsum[lane] : 0;
            #pragma unroll
            for (int o = 1; o < 16; o <<= 1) {
                int t = __shfl_up(y, o);
                if (lane >= o) y += t;
            }
            if (lane < 16) wsum[lane] = y;  // inclusive wave totals
        }
        __syncthreads();
        int wbase = (wid == 0) ? 0 : wsum[wid - 1];
        int r = running_s;
        int excl = r + wbase + x - v;
        if (i < n) { ofs[i] = excl; cursor[i] = excl; }
        __syncthreads();
        if (tid == 1023) running_s = r + wbase + x;  // += chunk total
        __syncthreads();
    }
    if (threadIdx.x == 0) ofs[n] = running_s;
}

// ---------------------------------------------------------------------------
// CSR fill: bucket src ids by dst (order within bucket is arbitrary)
// ---------------------------------------------------------------------------
__global__ void csr_fill_kernel(const int* __restrict__ src, const int* __restrict__ dst,
                                int* __restrict__ cursor, int* __restrict__ csr_src, int E) {
    int e = blockIdx.x * blockDim.x + threadIdx.x;
    if (e < E) {
        int d = dst[e];
        int pos = atomicAdd(&cursor[d], 1);
        csr_src[pos] = src[e];
    }
}

// ---------------------------------------------------------------------------
// Fused pull-gather: per dst node, one 64-lane wave.
//   aggG[d] = sum_{e: dst=d} dinv[src]*dinv[d] * h[src]  +  dinv[d]^2 * h[d]
//   mean[d] = (sum_{e: dst=d} h[src]) / max(deg,1)
// Reads each h[src] row once (512B coalesced), zero atomics.
// ---------------------------------------------------------------------------
__global__ __launch_bounds__(256) void fused_gather_kernel(
    const float* __restrict__ h,
    const int* __restrict__ csr_src,
    const int* __restrict__ ofs,
    const float* __restrict__ dinv,
    const float* __restrict__ rdegn,
    float* __restrict__ aggG,
    float* __restrict__ mean, int n)
{
    int wave = threadIdx.x >> 6;
    int lane = threadIdx.x & 63;
    int d = blockIdx.x * 4 + wave;
    if (d >= n) return;
    int beg = ofs[d], end = ofs[d + 1];
    float did = dinv[d];
    float2 aG = make_float2(0.f, 0.f);
    float2 aS = make_float2(0.f, 0.f);
    for (int p = beg; p < end; ++p) {
        int s = csr_src[p];
        float nr = dinv[s] * did;
        float2 v = *(const float2*)&h[(size_t)s * 128 + lane * 2];
        aG.x = fmaf(v.x, nr, aG.x);
        aG.y = fmaf(v.y, nr, aG.y);
        aS.x += v.x;
        aS.y += v.y;
    }
    float2 vd = *(const float2*)&h[(size_t)d * 128 + lane * 2];
    float sl = did * did;
    aG.x = fmaf(vd.x, sl, aG.x);
    aG.y = fmaf(vd.y, sl, aG.y);
    float rd = rdegn[d];
    aS.x *= rd; aS.y *= rd;
    *(float2*)&aggG[(size_t)d * 128 + lane * 2] = aG;
    *(float2*)&mean[(size_t)d * 128 + lane * 2] = aS;
}

// ---------------------------------------------------------------------------
// GEMM: C[n][128] = A[n][128] @ W[128][128] (+bias) (+accumulate)
// Block: 256 threads, 64 rows x 128 cols per block, BK=32 staged in LDS.
// In-place (C==A) is safe: each block reads only its own 64 A-rows and
// writes them only after the k-loop completes.
// ---------------------------------------------------------------------------
__global__ __launch_bounds__(256) void gemm_h128(
    const float* __restrict__ A, const float* __restrict__ W,
    float* __restrict__ C, const float* __restrict__ bias,
    int nrows, int accum)
{
    __shared__ float a_s[64][32];
    __shared__ float w_s[32][128];
    const int tid = threadIdx.x;
    const int tx  = tid & 31;   // column group: cols tx*4..tx*4+3
    const int ty  = tid >> 5;   // row group: rows ty*8..ty*8+7
    const int row0 = blockIdx.x * 64;

    float acc[8][4];
    #pragma unroll
    for (int i = 0; i < 8; i++)
        #pragma unroll
        for (int j = 0; j < 4; j++) acc[i][j] = 0.f;

    for (int kc = 0; kc < 128; kc += 32) {
        #pragma unroll
        for (int s = 0; s < 2; s++) {
            int q  = tid + s * 256;
            int r  = q >> 3;
            int c4 = (q & 7) * 4;
            int row = row0 + r;
            float4 v = make_float4(0.f, 0.f, 0.f, 0.f);
            if (row < nrows) v = *(const float4*)&A[(size_t)row * 128 + kc + c4];
            *(float4*)&a_s[r][c4] = v;
        }
        #pragma unroll
        for (int s = 0; s < 4; s++) {
            int q  = tid + s * 256;
            int r  = q >> 5;
            int c4 = (q & 31) * 4;
            *(float4*)&w_s[r][c4] = *(const float4*)&W[(size_t)(kc + r) * 128 + c4];
        }
        __syncthreads();
        #pragma unroll
        for (int k = 0; k < 32; k++) {
            float4 w4 = *(float4*)&w_s[k][tx * 4];
            #pragma unroll
            for (int i = 0; i < 8; i++) {
                float a = a_s[ty * 8 + i][k];
                acc[i][0] = fmaf(a, w4.x, acc[i][0]);
                acc[i][1] = fmaf(a, w4.y, acc[i][1]);
                acc[i][2] = fmaf(a, w4.z, acc[i][2]);
                acc[i][3] = fmaf(a, w4.w, acc[i][3]);
            }
        }
        __syncthreads();
    }

    float4 bv = make_float4(0.f, 0.f, 0.f, 0.f);
    if (bias) bv = *(const float4*)&bias[tx * 4];
    #pragma unroll
    for (int i = 0; i < 8; i++) {
        int row = row0 + ty * 8 + i;
        if (row >= nrows) continue;
        float4 o;
        o.x = acc[i][0] + bv.x;
        o.y = acc[i][1] + bv.y;
        o.z = acc[i][2] + bv.z;
        o.w = acc[i][3] + bv.w;
        float* cp = &C[(size_t)row * 128 + tx * 4];
        if (accum) {
            float4 c = *(float4*)cp;
            o.x += c.x; o.y += c.y; o.z += c.z; o.w += c.w;
        }
        *(float4*)cp = o;
    }
}

// ---------------------------------------------------------------------------
// Fused: conv blend -> LayerNorm blend -> activation blend -> skip accumulate
// One 64-lane wave per row (lane owns channels c and c+64).
// ---------------------------------------------------------------------------
__global__ __launch_bounds__(256) void fuse_combine_kernel(
    const float* __restrict__ agg, const float* __restrict__ hs,
    const float* __restrict__ aconv, const float* __restrict__ anorm,
    const float* __restrict__ aact,
    const float* __restrict__ lng, const float* __restrict__ lnb,
    float* __restrict__ h, float* __restrict__ skip, int first, int n)
{
    int wave = threadIdx.x >> 6;
    int lane = threadIdx.x & 63;
    int row = blockIdx.x * 4 + wave;
    if (row >= n) return;

    float c0 = aconv[0], c1 = aconv[1];
    float m = fmaxf(c0, c1);
    float e0 = expf(c0 - m), e1 = expf(c1 - m);
    float wc0 = e0 / (e0 + e1), wc1 = e1 / (e0 + e1);

    float q0 = anorm[0], q1 = anorm[1];
    m = fmaxf(q0, q1);
    e0 = expf(q0 - m); e1 = expf(q1 - m);
    float wn0 = e0 / (e0 + e1), wn1 = e1 / (e0 + e1);

    float a0 = aact[0], a1 = aact[1], a2 = aact[2];
    m = fmaxf(fmaxf(a0, a1), a2);
    float f0 = expf(a0 - m), f1 = expf(a1 - m), f2 = expf(a2 - m);
    float fs = f0 + f1 + f2;
    float wa0 = f0 / fs, wa1 = f1 / fs, wa2 = f2 / fs;

    size_t base = (size_t)row * 128;
    int cA = lane, cB = lane + 64;
    float t0 = wc0 * agg[base + cA] + wc1 * hs[base + cA];
    float t1 = wc0 * agg[base + cB] + wc1 * hs[base + cB];

    float s  = t0 + t1;
    float s2 = t0 * t0 + t1 * t1;
    #pragma unroll
    for (int o = 32; o; o >>= 1) {
        s  += __shfl_xor(s, o);
        s2 += __shfl_xor(s2, o);
    }
    float mu   = s * (1.f / 128.f);
    float var  = s2 * (1.f / 128.f) - mu * mu;
    float rstd = rsqrtf(var + EPSV);

    #pragma unroll
    for (int half = 0; half < 2; half++) {
        int c   = half ? cB : cA;
        float t = half ? t1 : t0;
        float ln = (t - mu) * rstd * lng[c] + lnb[c];
        float hv = wn0 * ln + wn1 * t;
        float rl = fmaxf(hv, 0.f);
        float th = tanhf(hv);
        float el = hv > 0.f ? hv : expm1f(hv);
        float out = wa0 * rl + wa1 * th + wa2 * el;
        h[base + c] = out;
        if (first) skip[base + c] = out;
        else       skip[base + c] += out;
    }
}

// ---------------------------------------------------------------------------
// Pooling: batch is sorted -> run-length accumulate in registers, few atomics
// ---------------------------------------------------------------------------
__global__ __launch_bounds__(256) void pool_sum_kernel(
    const float* __restrict__ skip, const int* __restrict__ batch,
    float* __restrict__ pooled, int n)
{
    int c   = threadIdx.x & 127;
    int seg = threadIdx.x >> 7;
    int n0  = blockIdx.x * 64 + seg * 32;
    int g_cur = -1;
    float acc = 0.f;
    for (int i = 0; i < 32; i++) {
        int node = n0 + i;
        if (node >= n) break;
        int g = batch[node];
        if (g != g_cur) {
            if (g_cur >= 0) atomicAdd(&pooled[(size_t)g_cur * 128 + c], acc);
            g_cur = g; acc = 0.f;
        }
        acc += skip[(size_t)node * 128 + c];
    }
    if (g_cur >= 0) atomicAdd(&pooled[(size_t)g_cur * 128 + c], acc);
}

// ---------------------------------------------------------------------------
// Final tiny GEMM: out[500][64] = pooled[500][128] @ post_w[128][64] + post_b
// ---------------------------------------------------------------------------
__global__ __launch_bounds__(64) void post_gemm_kernel(
    const float* __restrict__ pooled, const float* __restrict__ W,
    const float* __restrict__ b, float* __restrict__ out)
{
    __shared__ float p_s[128];
    int g = blockIdx.x;
    int j = threadIdx.x;
    p_s[j]      = pooled[(size_t)g * 128 + j];
    p_s[j + 64] = pooled[(size_t)g * 128 + 64 + j];
    __syncthreads();
    float acc = b[j];
    #pragma unroll
    for (int k = 0; k < 128; k++)
        acc = fmaf(p_s[k], W[k * 64 + j], acc);
    out[(size_t)g * 64 + j] = acc;
}

// ---------------------------------------------------------------------------
extern "C" void kernel_launch(void* const* d_in, const int* in_sizes, int n_in,
                              void* d_out, int out_size, void* d_ws, size_t ws_size,
                              hipStream_t stream)
{
    const float* x       = (const float*)d_in[0];
    const int*   ei      = (const int*)d_in[1];
    const int*   batch   = (const int*)d_in[2];
    const float* pre_w   = (const float*)d_in[3];
    const float* pre_b   = (const float*)d_in[4];
    const float* post_w  = (const float*)d_in[5];
    const float* post_b  = (const float*)d_in[6];
    const float* gcn_w   = (const float*)d_in[7];
    const float* gcn_b   = (const float*)d_in[8];
    const float* sage_ws = (const float*)d_in[9];
    const float* sage_wn = (const float*)d_in[10];
    const float* ln_g    = (const float*)d_in[11];
    const float* ln_b    = (const float*)d_in[12];
    const float* a_conv  = (const float*)d_in[13];
    const float* a_norm  = (const float*)d_in[14];
    const float* a_act   = (const float*)d_in[15];

    const int* src = ei;
    const int* dst = ei + N_EDGES;

    // workspace layout
    char* w = (char*)d_ws;
    const size_t NH = (size_t)N_NODES * 128 * sizeof(float);   // 25.6 MB
    float* h      = (float*)(w);
    float* aggG   = (float*)(w + NH);      // pre-agg, then GCN output (in-place gemm)
    float* mean   = (float*)(w + 2 * NH);
    float* hs     = (float*)(w + 3 * NH);
    float* skip   = (float*)(w + 4 * NH);
    float* dinv   = (float*)(w + 5 * NH);
    float* rdegn  = dinv + N_NODES;
    int*   cnt    = (int*)(rdegn + N_NODES);
    int*   ofs    = cnt + N_NODES;                 // N+1
    int*   cursor = ofs + N_NODES + 1;
    int*   csr_src= cursor + N_NODES;              // E
    float* pooled = (float*)(csr_src + N_EDGES);

    const int GEMM_BLOCKS = (N_NODES + 63) / 64;
    const int ROWWAVE_BLOCKS = (N_NODES + 3) / 4;

    // degrees + CSR build
    hipMemsetAsync(cnt, 0, N_NODES * sizeof(int), stream);
    count_deg_kernel<<<(N_EDGES + 255) / 256, 256, 0, stream>>>(dst, cnt, N_EDGES);
    finalize_deg_kernel<<<(N_NODES + 255) / 256, 256, 0, stream>>>(cnt, dinv, rdegn, N_NODES);
    scan_offsets_kernel<<<1, 1024, 0, stream>>>(cnt, ofs, cursor, N_NODES);
    csr_fill_kernel<<<(N_EDGES + 255) / 256, 256, 0, stream>>>(src, dst, cursor, csr_src, N_EDGES);

    // pre-MLP
    gemm_h128<<<GEMM_BLOCKS, 256, 0, stream>>>(x, pre_w, h, pre_b, N_NODES, 0);

    for (int l = 0; l < 2; l++) {
        // pull-gather: aggG = GCN-normalized sum of h (incl self loop); mean = SAGE mean
        fused_gather_kernel<<<ROWWAVE_BLOCKS, 256, 0, stream>>>(
            h, csr_src, ofs, dinv, rdegn, aggG, mean, N_NODES);
        // GCN: agg = aggG @ gcn_w + gcn_b   (in-place)
        gemm_h128<<<GEMM_BLOCKS, 256, 0, stream>>>(aggG, gcn_w + (size_t)l * 128 * 128,
                                                   aggG, gcn_b + l * 128, N_NODES, 0);
        // SAGE: hs = h @ sage_ws; hs += mean @ sage_wn
        gemm_h128<<<GEMM_BLOCKS, 256, 0, stream>>>(h, sage_ws + (size_t)l * 128 * 128,
                                                   hs, nullptr, N_NODES, 0);
        gemm_h128<<<GEMM_BLOCKS, 256, 0, stream>>>(mean, sage_wn + (size_t)l * 128 * 128,
                                                   hs, nullptr, N_NODES, 1);
        // combine + LayerNorm blend + activation blend + skip
        fuse_combine_kernel<<<ROWWAVE_BLOCKS, 256, 0, stream>>>(
            aggG, hs, a_conv + l * 2, a_norm + l * 2, a_act + l * 3,
            ln_g + l * 128, ln_b + l * 128, h, skip, (l == 0) ? 1 : 0, N_NODES);
    }

    // pooling + post-MLP
    hipMemsetAsync(pooled, 0, (size_t)G_GRAPHS * 128 * sizeof(float), stream);
    pool_sum_kernel<<<(N_NODES + 63) / 64, 256, 0, stream>>>(skip, batch, pooled, N_NODES);
    post_gemm_kernel<<<G_GRAPHS, 64, 0, stream>>>(pooled, post_w, post_b, (float*)d_out);
}

// Round 3
// 341.174 us; speedup vs baseline: 13.6794x; 1.7317x over previous
//
#include <hip/hip_runtime.h>
#include <math.h>

#define N_NODES 50000
#define N_EDGES 640000
#define HDIM    128
#define D_OUT   64
#define G_GRAPHS 500
#define EPSV    1e-5f
#define WPM     16384   // elements per packed 128x128 weight matrix

typedef __bf16 v8bf __attribute__((ext_vector_type(8)));
typedef float  f32x4 __attribute__((ext_vector_type(4)));

static __device__ __forceinline__ float bf_lo(unsigned u) {
    union { unsigned x; float f; } c; c.x = u << 16; return c.f;
}
static __device__ __forceinline__ float bf_hi(unsigned u) {
    union { unsigned x; float f; } c; c.x = u & 0xffff0000u; return c.f;
}

// ---------------------------------------------------------------------------
// Degrees
// ---------------------------------------------------------------------------
__global__ void count_deg_kernel(const int* __restrict__ dst, int* __restrict__ cnt, int E) {
    int i = blockIdx.x * blockDim.x + threadIdx.x;
    if (i < E) atomicAdd(&cnt[dst[i]], 1);
}

__global__ void finalize_deg_kernel(const int* __restrict__ cnt,
                                    float* __restrict__ dinv,
                                    float* __restrict__ rdegn, int n) {
    int i = blockIdx.x * blockDim.x + threadIdx.x;
    if (i < n) {
        float c = (float)cnt[i];
        dinv[i]  = rsqrtf(c + 1.0f);
        rdegn[i] = 1.0f / fmaxf(c, 1.0f);
    }
}

// ---------------------------------------------------------------------------
// 3-phase parallel exclusive scan (cnt -> ofs, cursor), 1024-elem chunks
// ---------------------------------------------------------------------------
__global__ __launch_bounds__(1024) void scan_block_kernel(
    const int* __restrict__ cnt, int* __restrict__ ofs,
    int* __restrict__ btot, int n)
{
    __shared__ int wsum[16];
    const int tid  = threadIdx.x;
    const int lane = tid & 63;
    const int wid  = tid >> 6;
    int i = blockIdx.x * 1024 + tid;
    int v = (i < n) ? cnt[i] : 0;
    int x = v;
    #pragma unroll
    for (int o = 1; o < 64; o <<= 1) {
        int t = __shfl_up(x, o);
        if (lane >= o) x += t;
    }
    if (lane == 63) wsum[wid] = x;
    __syncthreads();
    if (wid == 0) {
        int y = (lane < 16) ? wsum[lane] : 0;
        #pragma unroll
        for (int o = 1; o < 16; o <<= 1) {
            int t = __shfl_up(y, o);
            if (lane >= o) y += t;
        }
        if (lane < 16) wsum[lane] = y;
    }
    __syncthreads();
    int wbase = (wid == 0) ? 0 : wsum[wid - 1];
    if (i < n) ofs[i] = wbase + x - v;      // chunk-local exclusive
    if (tid == 1023) btot[blockIdx.x] = wbase + x;
}

__global__ __launch_bounds__(64) void scan_tot_kernel(
    const int* __restrict__ btot, int* __restrict__ bbase,
    int* __restrict__ ofs, int nb, int n)
{
    int i = threadIdx.x;
    int v = (i < nb) ? btot[i] : 0;
    int x = v;
    #pragma unroll
    for (int o = 1; o < 64; o <<= 1) {
        int t = __shfl_up(x, o);
        if (i >= o) x += t;
    }
    if (i < nb) bbase[i] = x - v;
    if (i == nb - 1) ofs[n] = x;            // total == E
}

__global__ void scan_add_kernel(int* __restrict__ ofs, int* __restrict__ cursor,
                                const int* __restrict__ bbase, int n) {
    int i = blockIdx.x * blockDim.x + threadIdx.x;
    if (i < n) {
        int o = ofs[i] + bbase[i >> 10];
        ofs[i] = o;
        cursor[i] = o;
    }
}

__global__ void csr_fill_kernel(const int* __restrict__ src, const int* __restrict__ dst,
                                int* __restrict__ cursor, int* __restrict__ csr_src, int E) {
    int e = blockIdx.x * blockDim.x + threadIdx.x;
    if (e < E) {
        int d = dst[e];
        int pos = atomicAdd(&cursor[d], 1);
        csr_src[pos] = src[e];
    }
}

// ---------------------------------------------------------------------------
// Pack 7 f32 128x128 weights into bf16 MFMA B-fragment order:
// Wp[m*WPM + ((kc*8+cb)*64 + lane)*8 + i] = W[kc*32+(lane>>4)*8+i][cb*16+(lane&15)]
// m: 0=pre_w, 1..2=gcn_w, 3..4=sage_ws, 5..6=sage_wn
// ---------------------------------------------------------------------------
__global__ void pack_weights_kernel(const float* __restrict__ pre_w,
                                    const float* __restrict__ gcn_w,
                                    const float* __restrict__ sws,
                                    const float* __restrict__ swn,
                                    __bf16* __restrict__ Wp)
{
    int t = blockIdx.x * blockDim.x + threadIdx.x;
    if (t >= 7 * 2048) return;
    int m    = t >> 11;
    int r    = t & 2047;
    int lane = r & 63;
    int fb   = r >> 6;           // kc*8 + cb
    int kc   = fb >> 3;
    int cb   = fb & 7;
    const float* W =
        (m == 0) ? pre_w :
        (m <= 2) ? gcn_w + (size_t)(m - 1) * WPM :
        (m <= 4) ? sws   + (size_t)(m - 3) * WPM :
                   swn   + (size_t)(m - 5) * WPM;
    int k0  = kc * 32 + (lane >> 4) * 8;
    int col = cb * 16 + (lane & 15);
    __bf16* out = Wp + (size_t)m * WPM + ((size_t)fb * 64 + lane) * 8;
    #pragma unroll
    for (int i = 0; i < 8; i++)
        out[i] = (__bf16)W[(size_t)(k0 + i) * 128 + col];
}

// ---------------------------------------------------------------------------
// Fused pull-gather (bf16 in/out, f32 accum). One wave per dst node,
// half-wave per edge (2 edges/iter), 8B loads.
// ---------------------------------------------------------------------------
__global__ __launch_bounds__(256) void fused_gather_bf16(
    const __bf16* __restrict__ hb,
    const int* __restrict__ csr_src,
    const int* __restrict__ ofs,
    const float* __restrict__ dinv,
    const float* __restrict__ rdegn,
    __bf16* __restrict__ aggGb,
    __bf16* __restrict__ meanb, int n)
{
    int w = threadIdx.x >> 6;
    int lane = threadIdx.x & 63;
    int d = blockIdx.x * 4 + w;
    if (d >= n) return;
    int beg = ofs[d], end = ofs[d + 1];
    float did = dinv[d];
    int half = lane >> 5;
    int c4 = (lane & 31) * 4;

    float aG0 = 0.f, aG1 = 0.f, aG2 = 0.f, aG3 = 0.f;
    float aS0 = 0.f, aS1 = 0.f, aS2 = 0.f, aS3 = 0.f;

    for (int p = beg; p < end; p += 2) {
        int pp = p + half;
        bool ok = pp < end;
        int s = csr_src[ok ? pp : beg];
        float nr = ok ? dinv[s] * did : 0.f;
        float mk = ok ? 1.f : 0.f;
        uint2 u = *(const uint2*)(hb + (size_t)s * 128 + c4);
        float v0 = bf_lo(u.x), v1 = bf_hi(u.x);
        float v2 = bf_lo(u.y), v3 = bf_hi(u.y);
        aG0 = fmaf(v0, nr, aG0); aG1 = fmaf(v1, nr, aG1);
        aG2 = fmaf(v2, nr, aG2); aG3 = fmaf(v3, nr, aG3);
        aS0 = fmaf(v0, mk, aS0); aS1 = fmaf(v1, mk, aS1);
        aS2 = fmaf(v2, mk, aS2); aS3 = fmaf(v3, mk, aS3);
    }
    aG0 += __shfl_xor(aG0, 32); aG1 += __shfl_xor(aG1, 32);
    aG2 += __shfl_xor(aG2, 32); aG3 += __shfl_xor(aG3, 32);
    aS0 += __shfl_xor(aS0, 32); aS1 += __shfl_xor(aS1, 32);
    aS2 += __shfl_xor(aS2, 32); aS3 += __shfl_xor(aS3, 32);

    if (half == 0) {
        uint2 ud = *(const uint2*)(hb + (size_t)d * 128 + c4);
        float sl = did * did;
        aG0 = fmaf(bf_lo(ud.x), sl, aG0);
        aG1 = fmaf(bf_hi(ud.x), sl, aG1);
        aG2 = fmaf(bf_lo(ud.y), sl, aG2);
        aG3 = fmaf(bf_hi(ud.y), sl, aG3);
        float rd = rdegn[d];
        union { __bf16 b[4]; uint2 u; } pg, pm;
        pg.b[0] = (__bf16)aG0; pg.b[1] = (__bf16)aG1;
        pg.b[2] = (__bf16)aG2; pg.b[3] = (__bf16)aG3;
        pm.b[0] = (__bf16)(aS0 * rd); pm.b[1] = (__bf16)(aS1 * rd);
        pm.b[2] = (__bf16)(aS2 * rd); pm.b[3] = (__bf16)(aS3 * rd);
        *(uint2*)(aggGb + (size_t)d * 128 + c4) = pg.u;
        *(uint2*)(meanb + (size_t)d * 128 + c4) = pm.u;
    }
}

// ---------------------------------------------------------------------------
// Pre-MLP: h_bf16 = x_f32 @ pre_w + pre_b, via MFMA (A converted in-register)
// Block 256 = 4 waves; wave = 16 rows x 128 cols.
// ---------------------------------------------------------------------------
__global__ __launch_bounds__(256) void pre_gemm_mfma(
    const float* __restrict__ x, const __bf16* __restrict__ Wp0,
    const float* __restrict__ pre_b, __bf16* __restrict__ hb, int n)
{
    int w = threadIdx.x >> 6;
    int lane = threadIdx.x & 63;
    int r0 = blockIdx.x * 64 + w * 16;
    if (r0 >= n) return;
    int rl = r0 + (lane & 15);
    if (rl >= n) rl = n - 1;
    int kg = lane >> 4;

    f32x4 acc[8];
    #pragma unroll
    for (int cb = 0; cb < 8; cb++) acc[cb] = (f32x4)(0.f);

    #pragma unroll
    for (int kc = 0; kc < 4; kc++) {
        const float* ap = x + (size_t)rl * 128 + kc * 32 + kg * 8;
        float4 a0 = *(const float4*)ap;
        float4 a1 = *(const float4*)(ap + 4);
        v8bf af;
        af[0] = (__bf16)a0.x; af[1] = (__bf16)a0.y;
        af[2] = (__bf16)a0.z; af[3] = (__bf16)a0.w;
        af[4] = (__bf16)a1.x; af[5] = (__bf16)a1.y;
        af[6] = (__bf16)a1.z; af[7] = (__bf16)a1.w;
        #pragma unroll
        for (int cb = 0; cb < 8; cb++) {
            v8bf bf = *(const v8bf*)(Wp0 + ((size_t)(kc * 8 + cb) * 64 + lane) * 8);
            acc[cb] = __builtin_amdgcn_mfma_f32_16x16x32_bf16(af, bf, acc[cb], 0, 0, 0);
        }
    }
    int cl = lane & 15;
    #pragma unroll
    for (int cb = 0; cb < 8; cb++) {
        float bias = pre_b[cb * 16 + cl];
        #pragma unroll
        for (int j = 0; j < 4; j++) {
            int r = r0 + kg * 4 + j;
            if (r < n) hb[(size_t)r * 128 + cb * 16 + cl] = (__bf16)(acc[cb][j] + bias);
        }
    }
}

// ---------------------------------------------------------------------------
// Fused layer: accG = aggG@Wg (+gcn_b), accS = h@Ws + mean@Wn, conv blend,
// LayerNorm blend, activation blend, write h (bf16) + skip (f32).
// ---------------------------------------------------------------------------
__global__ __launch_bounds__(256) void layer_fused_kernel(
    const __bf16* __restrict__ aggGb, const __bf16* __restrict__ hin,
    const __bf16* __restrict__ meanb,
    const __bf16* __restrict__ WpG, const __bf16* __restrict__ WpS,
    const __bf16* __restrict__ WpN,
    const float* __restrict__ gcn_b,
    const float* __restrict__ lng, const float* __restrict__ lnb,
    const float* __restrict__ aconv, const float* __restrict__ anorm,
    const float* __restrict__ aact,
    __bf16* __restrict__ hout, float* __restrict__ skip, int first, int n)
{
    int w = threadIdx.x >> 6;
    int lane = threadIdx.x & 63;
    int r0 = blockIdx.x * 64 + w * 16;
    if (r0 >= n) return;
    int rl = r0 + (lane & 15);
    if (rl >= n) rl = n - 1;
    int kg = lane >> 4;

    f32x4 accG[8], accS[8];
    #pragma unroll
    for (int cb = 0; cb < 8; cb++) { accG[cb] = (f32x4)(0.f); accS[cb] = (f32x4)(0.f); }

    #pragma unroll
    for (int kc = 0; kc < 4; kc++) {
        size_t ao = (size_t)rl * 128 + kc * 32 + kg * 8;
        v8bf ag = *(const v8bf*)(aggGb + ao);
        v8bf ah = *(const v8bf*)(hin   + ao);
        v8bf am = *(const v8bf*)(meanb + ao);
        #pragma unroll
        for (int cb = 0; cb < 8; cb++) {
            size_t bo = ((size_t)(kc * 8 + cb) * 64 + lane) * 8;
            v8bf bg = *(const v8bf*)(WpG + bo);
            v8bf bs = *(const v8bf*)(WpS + bo);
            v8bf bn = *(const v8bf*)(WpN + bo);
            accG[cb] = __builtin_amdgcn_mfma_f32_16x16x32_bf16(ag, bg, accG[cb], 0, 0, 0);
            accS[cb] = __builtin_amdgcn_mfma_f32_16x16x32_bf16(ah, bs, accS[cb], 0, 0, 0);
            accS[cb] = __builtin_amdgcn_mfma_f32_16x16x32_bf16(am, bn, accS[cb], 0, 0, 0);
        }
    }

    // architecture softmaxes
    float c0 = aconv[0], c1 = aconv[1];
    float m = fmaxf(c0, c1);
    float e0 = expf(c0 - m), e1 = expf(c1 - m);
    float wc0 = e0 / (e0 + e1), wc1 = e1 / (e0 + e1);
    float q0 = anorm[0], q1 = anorm[1];
    m = fmaxf(q0, q1);
    e0 = expf(q0 - m); e1 = expf(q1 - m);
    float wn0 = e0 / (e0 + e1), wn1 = e1 / (e0 + e1);
    float a0 = aact[0], a1 = aact[1], a2 = aact[2];
    m = fmaxf(fmaxf(a0, a1), a2);
    float f0 = expf(a0 - m), f1 = expf(a1 - m), f2 = expf(a2 - m);
    float fs = f0 + f1 + f2;
    float wa0 = f0 / fs, wa1 = f1 / fs, wa2 = f2 / fs;

    int cl = lane & 15;
    float gb[8], lg[8], lb[8];
    #pragma unroll
    for (int cb = 0; cb < 8; cb++) {
        int c = cb * 16 + cl;
        gb[cb] = gcn_b[c]; lg[cb] = lng[c]; lb[cb] = lnb[c];
    }

    // conv blend + row statistics
    float s[4] = {0, 0, 0, 0}, s2[4] = {0, 0, 0, 0};
    #pragma unroll
    for (int cb = 0; cb < 8; cb++)
        #pragma unroll
        for (int j = 0; j < 4; j++) {
            float tv = wc0 * (accG[cb][j] + gb[cb]) + wc1 * accS[cb][j];
            accG[cb][j] = tv;
            s[j] += tv;
            s2[j] = fmaf(tv, tv, s2[j]);
        }
    #pragma unroll
    for (int o = 1; o < 16; o <<= 1)
        #pragma unroll
        for (int j = 0; j < 4; j++) {
            s[j]  += __shfl_xor(s[j], o);
            s2[j] += __shfl_xor(s2[j], o);
        }
    float mu[4], rs[4];
    #pragma unroll
    for (int j = 0; j < 4; j++) {
        mu[j] = s[j] * (1.f / 128.f);
        float var = s2[j] * (1.f / 128.f) - mu[j] * mu[j];
        rs[j] = rsqrtf(var + EPSV);
    }

    #pragma unroll
    for (int j = 0; j < 4; j++) {
        int r = r0 + kg * 4 + j;
        if (r >= n) continue;
        #pragma unroll
        for (int cb = 0; cb < 8; cb++) {
            float tv = accG[cb][j];
            float ln = (tv - mu[j]) * rs[j] * lg[cb] + lb[cb];
            float hv = wn0 * ln + wn1 * tv;
            float rl_ = fmaxf(hv, 0.f);
            float th = tanhf(hv);
            float el = hv > 0.f ? hv : expm1f(hv);
            float out = wa0 * rl_ + wa1 * th + wa2 * el;
            size_t idx = (size_t)r * 128 + cb * 16 + cl;
            hout[idx] = (__bf16)out;
            if (first) skip[idx] = out;
            else       skip[idx] += out;
        }
    }
}

// ---------------------------------------------------------------------------
// Pooling (skip f32; batch sorted)
// ---------------------------------------------------------------------------
__global__ __launch_bounds__(256) void pool_sum_kernel(
    const float* __restrict__ skip, const int* __restrict__ batch,
    float* __restrict__ pooled, int n)
{
    int c   = threadIdx.x & 127;
    int seg = threadIdx.x >> 7;
    int n0  = blockIdx.x * 64 + seg * 32;
    int g_cur = -1;
    float acc = 0.f;
    for (int i = 0; i < 32; i++) {
        int node = n0 + i;
        if (node >= n) break;
        int g = batch[node];
        if (g != g_cur) {
            if (g_cur >= 0) atomicAdd(&pooled[(size_t)g_cur * 128 + c], acc);
            g_cur = g; acc = 0.f;
        }
        acc += skip[(size_t)node * 128 + c];
    }
    if (g_cur >= 0) atomicAdd(&pooled[(size_t)g_cur * 128 + c], acc);
}

__global__ __launch_bounds__(64) void post_gemm_kernel(
    const float* __restrict__ pooled, const float* __restrict__ W,
    const float* __restrict__ b, float* __restrict__ out)
{
    __shared__ float p_s[128];
    int g = blockIdx.x;
    int j = threadIdx.x;
    p_s[j]      = pooled[(size_t)g * 128 + j];
    p_s[j + 64] = pooled[(size_t)g * 128 + 64 + j];
    __syncthreads();
    float acc = b[j];
    #pragma unroll
    for (int k = 0; k < 128; k++)
        acc = fmaf(p_s[k], W[k * 64 + j], acc);
    out[(size_t)g * 64 + j] = acc;
}

// ---------------------------------------------------------------------------
extern "C" void kernel_launch(void* const* d_in, const int* in_sizes, int n_in,
                              void* d_out, int out_size, void* d_ws, size_t ws_size,
                              hipStream_t stream)
{
    const float* x       = (const float*)d_in[0];
    const int*   ei      = (const int*)d_in[1];
    const int*   batch   = (const int*)d_in[2];
    const float* pre_w   = (const float*)d_in[3];
    const float* pre_b   = (const float*)d_in[4];
    const float* post_w  = (const float*)d_in[5];
    const float* post_b  = (const float*)d_in[6];
    const float* gcn_w   = (const float*)d_in[7];
    const float* gcn_b   = (const float*)d_in[8];
    const float* sage_ws = (const float*)d_in[9];
    const float* sage_wn = (const float*)d_in[10];
    const float* ln_g    = (const float*)d_in[11];
    const float* ln_b    = (const float*)d_in[12];
    const float* a_conv  = (const float*)d_in[13];
    const float* a_norm  = (const float*)d_in[14];
    const float* a_act   = (const float*)d_in[15];

    const int* src = ei;
    const int* dst = ei + N_EDGES;

    // workspace layout (256B-aligned slices)
    char* wsp = (char*)d_ws;
    size_t off = 0;
    auto alloc = [&](size_t bytes) {
        char* p = wsp + off;
        off += (bytes + 255) & ~(size_t)255;
        return p;
    };
    const size_t NHB = (size_t)N_NODES * 128 * sizeof(__bf16);   // 12.8 MB
    __bf16* hb     = (__bf16*)alloc(NHB);
    __bf16* aggGb  = (__bf16*)alloc(NHB);
    __bf16* meanb  = (__bf16*)alloc(NHB);
    float*  skip   = (float*)alloc((size_t)N_NODES * 128 * sizeof(float));
    __bf16* Wp     = (__bf16*)alloc((size_t)7 * WPM * sizeof(__bf16));
    float*  dinv   = (float*)alloc(N_NODES * sizeof(float));
    float*  rdegn  = (float*)alloc(N_NODES * sizeof(float));
    int*    cnt    = (int*)alloc(N_NODES * sizeof(int));
    int*    ofs    = (int*)alloc((N_NODES + 1) * sizeof(int));
    int*    cursor = (int*)alloc(N_NODES * sizeof(int));
    int*    csr_src= (int*)alloc(N_EDGES * sizeof(int));
    float*  pooled = (float*)alloc((size_t)G_GRAPHS * 128 * sizeof(float));
    int*    btot   = (int*)alloc(64 * sizeof(int));
    int*    bbase  = (int*)alloc(64 * sizeof(int));

    const int NB_SCAN = (N_NODES + 1023) / 1024;      // 49
    const int GEMM_BLOCKS = (N_NODES + 63) / 64;      // 782
    const int GATHER_BLOCKS = (N_NODES + 3) / 4;

    // weights pack (independent of graph build)
    pack_weights_kernel<<<(7 * 2048 + 255) / 256, 256, 0, stream>>>(
        pre_w, gcn_w, sage_ws, sage_wn, Wp);

    // degrees + CSR
    hipMemsetAsync(cnt, 0, N_NODES * sizeof(int), stream);
    count_deg_kernel<<<(N_EDGES + 255) / 256, 256, 0, stream>>>(dst, cnt, N_EDGES);
    finalize_deg_kernel<<<(N_NODES + 255) / 256, 256, 0, stream>>>(cnt, dinv, rdegn, N_NODES);
    scan_block_kernel<<<NB_SCAN, 1024, 0, stream>>>(cnt, ofs, btot, N_NODES);
    scan_tot_kernel<<<1, 64, 0, stream>>>(btot, bbase, ofs, NB_SCAN, N_NODES);
    scan_add_kernel<<<(N_NODES + 255) / 256, 256, 0, stream>>>(ofs, cursor, bbase, N_NODES);
    csr_fill_kernel<<<(N_EDGES + 255) / 256, 256, 0, stream>>>(src, dst, cursor, csr_src, N_EDGES);

    // pre-MLP (f32 x -> bf16 h)
    pre_gemm_mfma<<<GEMM_BLOCKS, 256, 0, stream>>>(x, Wp, pre_b, hb, N_NODES);

    for (int l = 0; l < 2; l++) {
        fused_gather_bf16<<<GATHER_BLOCKS, 256, 0, stream>>>(
            hb, csr_src, ofs, dinv, rdegn, aggGb, meanb, N_NODES);
        layer_fused_kernel<<<GEMM_BLOCKS, 256, 0, stream>>>(
            aggGb, hb, meanb,
            Wp + (size_t)(1 + l) * WPM, Wp + (size_t)(3 + l) * WPM, Wp + (size_t)(5 + l) * WPM,
            gcn_b + l * 128, ln_g + l * 128, ln_b + l * 128,
            a_conv + l * 2, a_norm + l * 2, a_act + l * 3,
            hb, skip, (l == 0) ? 1 : 0, N_NODES);
    }

    hipMemsetAsync(pooled, 0, (size_t)G_GRAPHS * 128 * sizeof(float), stream);
    pool_sum_kernel<<<(N_NODES + 63) / 64, 256, 0, stream>>>(skip, batch, pooled, N_NODES);
    post_gemm_kernel<<<G_GRAPHS, 64, 0, stream>>>(pooled, post_w, post_b, (float*)d_out);
}

// Round 4
// 256.569 us; speedup vs baseline: 18.1903x; 1.3298x over previous
//
#include <hip/hip_runtime.h>
#include <math.h>

#define N_NODES 50000
#define N_EDGES 640000
#define HDIM    128
#define D_OUT   64
#define G_GRAPHS 500
#define EPSV    1e-5f
#define WPM     16384   // elements per packed 128x128 weight matrix

typedef __bf16 v8bf __attribute__((ext_vector_type(8)));
typedef float  f32x4 __attribute__((ext_vector_type(4)));

static __device__ __forceinline__ float bf_lo(unsigned u) {
    union { unsigned x; float f; } c; c.x = u << 16; return c.f;
}
static __device__ __forceinline__ float bf_hi(unsigned u) {
    union { unsigned x; float f; } c; c.x = u & 0xffff0000u; return c.f;
}

// ---------------------------------------------------------------------------
// Degrees
// ---------------------------------------------------------------------------
__global__ void count_deg_kernel(const int* __restrict__ dst, int* __restrict__ cnt, int E) {
    int i = blockIdx.x * blockDim.x + threadIdx.x;
    if (i < E) atomicAdd(&cnt[dst[i]], 1);
}

__global__ void finalize_deg_kernel(const int* __restrict__ cnt,
                                    float* __restrict__ dinv,
                                    float* __restrict__ rdegn, int n) {
    int i = blockIdx.x * blockDim.x + threadIdx.x;
    if (i < n) {
        float c = (float)cnt[i];
        dinv[i]  = rsqrtf(c + 1.0f);
        rdegn[i] = 1.0f / fmaxf(c, 1.0f);
    }
}

// ---------------------------------------------------------------------------
// 3-phase parallel exclusive scan (cnt -> ofs, cursor)
// ---------------------------------------------------------------------------
__global__ __launch_bounds__(1024) void scan_block_kernel(
    const int* __restrict__ cnt, int* __restrict__ ofs,
    int* __restrict__ btot, int n)
{
    __shared__ int wsum[16];
    const int tid  = threadIdx.x;
    const int lane = tid & 63;
    const int wid  = tid >> 6;
    int i = blockIdx.x * 1024 + tid;
    int v = (i < n) ? cnt[i] : 0;
    int x = v;
    #pragma unroll
    for (int o = 1; o < 64; o <<= 1) {
        int t = __shfl_up(x, o);
        if (lane >= o) x += t;
    }
    if (lane == 63) wsum[wid] = x;
    __syncthreads();
    if (wid == 0) {
        int y = (lane < 16) ? wsum[lane] : 0;
        #pragma unroll
        for (int o = 1; o < 16; o <<= 1) {
            int t = __shfl_up(y, o);
            if (lane >= o) y += t;
        }
        if (lane < 16) wsum[lane] = y;
    }
    __syncthreads();
    int wbase = (wid == 0) ? 0 : wsum[wid - 1];
    if (i < n) ofs[i] = wbase + x - v;
    if (tid == 1023) btot[blockIdx.x] = wbase + x;
}

__global__ __launch_bounds__(64) void scan_tot_kernel(
    const int* __restrict__ btot, int* __restrict__ bbase,
    int* __restrict__ ofs, int nb, int n)
{
    int i = threadIdx.x;
    int v = (i < nb) ? btot[i] : 0;
    int x = v;
    #pragma unroll
    for (int o = 1; o < 64; o <<= 1) {
        int t = __shfl_up(x, o);
        if (i >= o) x += t;
    }
    if (i < nb) bbase[i] = x - v;
    if (i == nb - 1) ofs[n] = x;
}

__global__ void scan_add_kernel(int* __restrict__ ofs, int* __restrict__ cursor,
                                const int* __restrict__ bbase, int n) {
    int i = blockIdx.x * blockDim.x + threadIdx.x;
    if (i < n) {
        int o = ofs[i] + bbase[i >> 10];
        ofs[i] = o;
        cursor[i] = o;
    }
}

__global__ void csr_fill_kernel(const int* __restrict__ src, const int* __restrict__ dst,
                                int* __restrict__ cursor, int* __restrict__ csr_src, int E) {
    int e = blockIdx.x * blockDim.x + threadIdx.x;
    if (e < E) {
        int d = dst[e];
        int pos = atomicAdd(&cursor[d], 1);
        csr_src[pos] = src[e];
    }
}

// ---------------------------------------------------------------------------
// Pack 7 f32 128x128 weights into bf16 MFMA B-fragment order, with the
// conv-softmax weights FOLDED IN (pack runs every call; a_conv is an input):
//   m=0: pre_w (scale 1)
//   m=1,2: wc0[l] * gcn_w[l]     m=3,4: wc1[l] * sage_ws[l]
//   m=5,6: wc1[l] * sage_wn[l]
// Wp[m*WPM + ((kc*8+cb)*64 + lane)*8 + i] = s*W[kc*32+(lane>>4)*8+i][cb*16+(lane&15)]
// ---------------------------------------------------------------------------
__global__ void pack_weights_kernel(const float* __restrict__ pre_w,
                                    const float* __restrict__ gcn_w,
                                    const float* __restrict__ sws,
                                    const float* __restrict__ swn,
                                    const float* __restrict__ a_conv,
                                    __bf16* __restrict__ Wp)
{
    int t = blockIdx.x * blockDim.x + threadIdx.x;
    if (t >= 7 * 2048) return;
    int m    = t >> 11;
    int r    = t & 2047;
    int lane = r & 63;
    int fb   = r >> 6;           // kc*8 + cb
    int kc   = fb >> 3;
    int cb   = fb & 7;
    const float* W = pre_w;
    float scale = 1.f;
    if (m > 0) {
        int type = (m - 1) >> 1;     // 0=gcn, 1=sage_ws, 2=sage_wn
        int l    = (m - 1) & 1;
        float c0 = a_conv[l * 2], c1 = a_conv[l * 2 + 1];
        float mx = fmaxf(c0, c1);
        float e0 = __expf(c0 - mx), e1 = __expf(c1 - mx);
        float wc0 = e0 / (e0 + e1);
        scale = (type == 0) ? wc0 : (1.f - wc0);
        W = (type == 0) ? gcn_w + (size_t)l * WPM
          : (type == 1) ? sws   + (size_t)l * WPM
                        : swn   + (size_t)l * WPM;
    }
    int k0  = kc * 32 + (lane >> 4) * 8;
    int col = cb * 16 + (lane & 15);
    __bf16* out = Wp + (size_t)m * WPM + ((size_t)fb * 64 + lane) * 8;
    #pragma unroll
    for (int i = 0; i < 8; i++)
        out[i] = (__bf16)(scale * W[(size_t)(k0 + i) * 128 + col]);
}

// ---------------------------------------------------------------------------
// Fused pull-gather (bf16): one wave per dst node, 4 edges per iteration
// (16 lanes x 16B per 256B row). f32 accumulation, quarter-reduce via shfl.
// ---------------------------------------------------------------------------
__global__ __launch_bounds__(256) void fused_gather_bf16(
    const __bf16* __restrict__ hb,
    const int* __restrict__ csr_src,
    const int* __restrict__ ofs,
    const float* __restrict__ dinv,
    const float* __restrict__ rdegn,
    __bf16* __restrict__ aggGb,
    __bf16* __restrict__ meanb, int n)
{
    int w = threadIdx.x >> 6;
    int lane = threadIdx.x & 63;
    int d = blockIdx.x * 4 + w;
    if (d >= n) return;
    int beg = ofs[d], end = ofs[d + 1];
    float did = dinv[d];
    int q  = lane >> 4;          // quarter: which edge of the group of 4
    int c8 = (lane & 15) * 8;    // 8 channels (16B) per lane

    float aG[8] = {0, 0, 0, 0, 0, 0, 0, 0};
    float aS[8] = {0, 0, 0, 0, 0, 0, 0, 0};

    for (int p = beg; p < end; p += 4) {
        int pp = p + q;
        bool ok = pp < end;
        int s = csr_src[ok ? pp : beg];
        float nr = ok ? dinv[s] * did : 0.f;
        float mk = ok ? 1.f : 0.f;
        uint4 u = *(const uint4*)(hb + (size_t)s * 128 + c8);
        float v[8] = { bf_lo(u.x), bf_hi(u.x), bf_lo(u.y), bf_hi(u.y),
                       bf_lo(u.z), bf_hi(u.z), bf_lo(u.w), bf_hi(u.w) };
        #pragma unroll
        for (int i = 0; i < 8; i++) {
            aG[i] = fmaf(v[i], nr, aG[i]);
            aS[i] = fmaf(v[i], mk, aS[i]);
        }
    }
    #pragma unroll
    for (int i = 0; i < 8; i++) {
        aG[i] += __shfl_xor(aG[i], 16);
        aG[i] += __shfl_xor(aG[i], 32);
        aS[i] += __shfl_xor(aS[i], 16);
        aS[i] += __shfl_xor(aS[i], 32);
    }

    if (q == 0) {
        uint4 ud = *(const uint4*)(hb + (size_t)d * 128 + c8);
        float vd[8] = { bf_lo(ud.x), bf_hi(ud.x), bf_lo(ud.y), bf_hi(ud.y),
                        bf_lo(ud.z), bf_hi(ud.z), bf_lo(ud.w), bf_hi(ud.w) };
        float sl = did * did;
        float rd = rdegn[d];
        union { __bf16 b[8]; uint4 u; } pg, pm;
        #pragma unroll
        for (int i = 0; i < 8; i++) {
            pg.b[i] = (__bf16)fmaf(vd[i], sl, aG[i]);
            pm.b[i] = (__bf16)(aS[i] * rd);
        }
        *(uint4*)(aggGb + (size_t)d * 128 + c8) = pg.u;
        *(uint4*)(meanb + (size_t)d * 128 + c8) = pm.u;
    }
}

// ---------------------------------------------------------------------------
// Pre-MLP: h_bf16 = x_f32 @ pre_w + pre_b, via MFMA
// ---------------------------------------------------------------------------
__global__ __launch_bounds__(256) void pre_gemm_mfma(
    const float* __restrict__ x, const __bf16* __restrict__ Wp0,
    const float* __restrict__ pre_b, __bf16* __restrict__ hb, int n)
{
    int w = threadIdx.x >> 6;
    int lane = threadIdx.x & 63;
    int r0 = blockIdx.x * 64 + w * 16;
    if (r0 >= n) return;
    int rl = r0 + (lane & 15);
    if (rl >= n) rl = n - 1;
    int kg = lane >> 4;

    f32x4 acc[8];
    #pragma unroll
    for (int cb = 0; cb < 8; cb++) acc[cb] = (f32x4)(0.f);

    #pragma unroll
    for (int kc = 0; kc < 4; kc++) {
        const float* ap = x + (size_t)rl * 128 + kc * 32 + kg * 8;
        float4 a0 = *(const float4*)ap;
        float4 a1 = *(const float4*)(ap + 4);
        v8bf af;
        af[0] = (__bf16)a0.x; af[1] = (__bf16)a0.y;
        af[2] = (__bf16)a0.z; af[3] = (__bf16)a0.w;
        af[4] = (__bf16)a1.x; af[5] = (__bf16)a1.y;
        af[6] = (__bf16)a1.z; af[7] = (__bf16)a1.w;
        #pragma unroll
        for (int cb = 0; cb < 8; cb++) {
            v8bf bf = *(const v8bf*)(Wp0 + ((size_t)(kc * 8 + cb) * 64 + lane) * 8);
            acc[cb] = __builtin_amdgcn_mfma_f32_16x16x32_bf16(af, bf, acc[cb], 0, 0, 0);
        }
    }
    int cl = lane & 15;
    #pragma unroll
    for (int cb = 0; cb < 8; cb++) {
        float bias = pre_b[cb * 16 + cl];
        #pragma unroll
        for (int j = 0; j < 4; j++) {
            int r = r0 + kg * 4 + j;
            if (r < n) hb[(size_t)r * 128 + cb * 16 + cl] = (__bf16)(acc[cb][j] + bias);
        }
    }
}

// ---------------------------------------------------------------------------
// Fused layer: single K=384 MFMA stream (conv softmax folded into weights):
//   acc = aggG@(wc0 Wg) + h@(wc1 Ws) + mean@(wc1 Wn); tv = acc + wc0*gcn_b
// then LayerNorm blend + activation blend (native transcendentals),
// write h_out (bf16) only.
// ---------------------------------------------------------------------------
__global__ __launch_bounds__(256) void layer_fused_kernel(
    const __bf16* __restrict__ aggGb, const __bf16* __restrict__ hin,
    const __bf16* __restrict__ meanb,
    const __bf16* __restrict__ WpG, const __bf16* __restrict__ WpS,
    const __bf16* __restrict__ WpN,
    const float* __restrict__ gcn_b,
    const float* __restrict__ lng, const float* __restrict__ lnb,
    const float* __restrict__ aconv, const float* __restrict__ anorm,
    const float* __restrict__ aact,
    __bf16* __restrict__ hout, int n)
{
    int w = threadIdx.x >> 6;
    int lane = threadIdx.x & 63;
    int r0 = blockIdx.x * 64 + w * 16;
    if (r0 >= n) return;
    int rl = r0 + (lane & 15);
    if (rl >= n) rl = n - 1;
    int kg = lane >> 4;

    f32x4 acc[8];
    #pragma unroll
    for (int cb = 0; cb < 8; cb++) acc[cb] = (f32x4)(0.f);

    // hoist all 12 A-fragments (max memory-level parallelism)
    v8bf af[12];
    #pragma unroll
    for (int kc = 0; kc < 4; kc++) {
        size_t ao = (size_t)rl * 128 + kc * 32 + kg * 8;
        af[kc]     = *(const v8bf*)(aggGb + ao);
        af[4 + kc] = *(const v8bf*)(hin   + ao);
        af[8 + kc] = *(const v8bf*)(meanb + ao);
    }
    #pragma unroll
    for (int kc = 0; kc < 4; kc++) {
        #pragma unroll
        for (int cb = 0; cb < 8; cb++) {
            size_t bo = ((size_t)(kc * 8 + cb) * 64 + lane) * 8;
            acc[cb] = __builtin_amdgcn_mfma_f32_16x16x32_bf16(
                af[kc], *(const v8bf*)(WpG + bo), acc[cb], 0, 0, 0);
            acc[cb] = __builtin_amdgcn_mfma_f32_16x16x32_bf16(
                af[4 + kc], *(const v8bf*)(WpS + bo), acc[cb], 0, 0, 0);
            acc[cb] = __builtin_amdgcn_mfma_f32_16x16x32_bf16(
                af[8 + kc], *(const v8bf*)(WpN + bo), acc[cb], 0, 0, 0);
        }
    }

    // architecture softmaxes (native exp)
    float c0 = aconv[0], c1 = aconv[1];
    float m = fmaxf(c0, c1);
    float e0 = __expf(c0 - m), e1 = __expf(c1 - m);
    float wc0 = e0 / (e0 + e1);
    float q0 = anorm[0], q1 = anorm[1];
    m = fmaxf(q0, q1);
    e0 = __expf(q0 - m); e1 = __expf(q1 - m);
    float wn0 = e0 / (e0 + e1), wn1 = 1.f - wn0;
    float a0 = aact[0], a1 = aact[1], a2 = aact[2];
    m = fmaxf(fmaxf(a0, a1), a2);
    float f0 = __expf(a0 - m), f1 = __expf(a1 - m), f2 = __expf(a2 - m);
    float fs = 1.f / (f0 + f1 + f2);
    float wa0 = f0 * fs, wa1 = f1 * fs, wa2 = f2 * fs;

    int cl = lane & 15;
    float gbF[8], lg[8], lb[8];
    #pragma unroll
    for (int cb = 0; cb < 8; cb++) {
        int c = cb * 16 + cl;
        gbF[cb] = wc0 * gcn_b[c]; lg[cb] = lng[c]; lb[cb] = lnb[c];
    }

    // bias + row statistics
    float s[4] = {0, 0, 0, 0}, s2[4] = {0, 0, 0, 0};
    #pragma unroll
    for (int cb = 0; cb < 8; cb++)
        #pragma unroll
        for (int j = 0; j < 4; j++) {
            float tv = acc[cb][j] + gbF[cb];
            acc[cb][j] = tv;
            s[j] += tv;
            s2[j] = fmaf(tv, tv, s2[j]);
        }
    #pragma unroll
    for (int o = 1; o < 16; o <<= 1)
        #pragma unroll
        for (int j = 0; j < 4; j++) {
            s[j]  += __shfl_xor(s[j], o);
            s2[j] += __shfl_xor(s2[j], o);
        }
    float mu[4], rs[4];
    #pragma unroll
    for (int j = 0; j < 4; j++) {
        mu[j] = s[j] * (1.f / 128.f);
        float var = s2[j] * (1.f / 128.f) - mu[j] * mu[j];
        rs[j] = rsqrtf(var + EPSV);
    }

    #pragma unroll
    for (int j = 0; j < 4; j++) {
        int r = r0 + kg * 4 + j;
        if (r >= n) continue;
        #pragma unroll
        for (int cb = 0; cb < 8; cb++) {
            float tv = acc[cb][j];
            float ln = (tv - mu[j]) * rs[j] * lg[cb] + lb[cb];
            float hv = wn0 * ln + wn1 * tv;
            float rl_ = fmaxf(hv, 0.f);
            float ex2 = __expf(2.f * hv);
            float th = 1.f - 2.f * __builtin_amdgcn_rcpf(ex2 + 1.f);
            float el = hv > 0.f ? hv : __expf(hv) - 1.f;
            float out = wa0 * rl_ + wa1 * th + wa2 * el;
            hout[(size_t)r * 128 + cb * 16 + cl] = (__bf16)out;
        }
    }
}

// ---------------------------------------------------------------------------
// Pooling: sum h1+h2 (bf16), batch sorted -> run-length accumulate.
// Thread owns 2 channels (4B loads); block covers 128 nodes.
// ---------------------------------------------------------------------------
__global__ __launch_bounds__(256) void pool_sum_kernel(
    const __bf16* __restrict__ h1, const __bf16* __restrict__ h2,
    const int* __restrict__ batch, float* __restrict__ pooled, int n)
{
    int c2  = (threadIdx.x & 63) * 2;
    int seg = threadIdx.x >> 6;
    int n0  = blockIdx.x * 128 + seg * 32;
    int g_cur = -1;
    float acc0 = 0.f, acc1 = 0.f;
    for (int i = 0; i < 32; i++) {
        int node = n0 + i;
        if (node >= n) break;
        int g = batch[node];
        if (g != g_cur) {
            if (g_cur >= 0) {
                atomicAdd(&pooled[(size_t)g_cur * 128 + c2], acc0);
                atomicAdd(&pooled[(size_t)g_cur * 128 + c2 + 1], acc1);
            }
            g_cur = g; acc0 = 0.f; acc1 = 0.f;
        }
        unsigned u1 = *(const unsigned*)(h1 + (size_t)node * 128 + c2);
        unsigned u2 = *(const unsigned*)(h2 + (size_t)node * 128 + c2);
        acc0 += bf_lo(u1) + bf_lo(u2);
        acc1 += bf_hi(u1) + bf_hi(u2);
    }
    if (g_cur >= 0) {
        atomicAdd(&pooled[(size_t)g_cur * 128 + c2], acc0);
        atomicAdd(&pooled[(size_t)g_cur * 128 + c2 + 1], acc1);
    }
}

__global__ __launch_bounds__(64) void post_gemm_kernel(
    const float* __restrict__ pooled, const float* __restrict__ W,
    const float* __restrict__ b, float* __restrict__ out)
{
    __shared__ float p_s[128];
    int g = blockIdx.x;
    int j = threadIdx.x;
    p_s[j]      = pooled[(size_t)g * 128 + j];
    p_s[j + 64] = pooled[(size_t)g * 128 + 64 + j];
    __syncthreads();
    float acc = b[j];
    #pragma unroll
    for (int k = 0; k < 128; k++)
        acc = fmaf(p_s[k], W[k * 64 + j], acc);
    out[(size_t)g * 64 + j] = acc;
}

// ---------------------------------------------------------------------------
extern "C" void kernel_launch(void* const* d_in, const int* in_sizes, int n_in,
                              void* d_out, int out_size, void* d_ws, size_t ws_size,
                              hipStream_t stream)
{
    const float* x       = (const float*)d_in[0];
    const int*   ei      = (const int*)d_in[1];
    const int*   batch   = (const int*)d_in[2];
    const float* pre_w   = (const float*)d_in[3];
    const float* pre_b   = (const float*)d_in[4];
    const float* post_w  = (const float*)d_in[5];
    const float* post_b  = (const float*)d_in[6];
    const float* gcn_w   = (const float*)d_in[7];
    const float* gcn_b   = (const float*)d_in[8];
    const float* sage_ws = (const float*)d_in[9];
    const float* sage_wn = (const float*)d_in[10];
    const float* ln_g    = (const float*)d_in[11];
    const float* ln_b    = (const float*)d_in[12];
    const float* a_conv  = (const float*)d_in[13];
    const float* a_norm  = (const float*)d_in[14];
    const float* a_act   = (const float*)d_in[15];

    const int* src = ei;
    const int* dst = ei + N_EDGES;

    char* wsp = (char*)d_ws;
    size_t off = 0;
    auto alloc = [&](size_t bytes) {
        char* p = wsp + off;
        off += (bytes + 255) & ~(size_t)255;
        return p;
    };
    const size_t NHB = (size_t)N_NODES * 128 * sizeof(__bf16);   // 12.8 MB
    __bf16* hb0    = (__bf16*)alloc(NHB);   // pre-MLP output
    __bf16* h1b    = (__bf16*)alloc(NHB);   // layer-1 output
    __bf16* h2b    = (__bf16*)alloc(NHB);   // layer-2 output
    __bf16* aggGb  = (__bf16*)alloc(NHB);
    __bf16* meanb  = (__bf16*)alloc(NHB);
    __bf16* Wp     = (__bf16*)alloc((size_t)7 * WPM * sizeof(__bf16));
    float*  dinv   = (float*)alloc(N_NODES * sizeof(float));
    float*  rdegn  = (float*)alloc(N_NODES * sizeof(float));
    int*    cnt    = (int*)alloc(N_NODES * sizeof(int));
    int*    ofs    = (int*)alloc((N_NODES + 1) * sizeof(int));
    int*    cursor = (int*)alloc(N_NODES * sizeof(int));
    int*    csr_src= (int*)alloc(N_EDGES * sizeof(int));
    float*  pooled = (float*)alloc((size_t)G_GRAPHS * 128 * sizeof(float));
    int*    btot   = (int*)alloc(64 * sizeof(int));
    int*    bbase  = (int*)alloc(64 * sizeof(int));

    const int NB_SCAN = (N_NODES + 1023) / 1024;
    const int GEMM_BLOCKS = (N_NODES + 63) / 64;
    const int GATHER_BLOCKS = (N_NODES + 3) / 4;

    pack_weights_kernel<<<(7 * 2048 + 255) / 256, 256, 0, stream>>>(
        pre_w, gcn_w, sage_ws, sage_wn, a_conv, Wp);

    hipMemsetAsync(cnt, 0, N_NODES * sizeof(int), stream);
    count_deg_kernel<<<(N_EDGES + 255) / 256, 256, 0, stream>>>(dst, cnt, N_EDGES);
    finalize_deg_kernel<<<(N_NODES + 255) / 256, 256, 0, stream>>>(cnt, dinv, rdegn, N_NODES);
    scan_block_kernel<<<NB_SCAN, 1024, 0, stream>>>(cnt, ofs, btot, N_NODES);
    scan_tot_kernel<<<1, 64, 0, stream>>>(btot, bbase, ofs, NB_SCAN, N_NODES);
    scan_add_kernel<<<(N_NODES + 255) / 256, 256, 0, stream>>>(ofs, cursor, bbase, N_NODES);
    csr_fill_kernel<<<(N_EDGES + 255) / 256, 256, 0, stream>>>(src, dst, cursor, csr_src, N_EDGES);

    pre_gemm_mfma<<<GEMM_BLOCKS, 256, 0, stream>>>(x, Wp, pre_b, hb0, N_NODES);

    const __bf16* hin[2]  = { hb0, h1b };
    __bf16*       hout[2] = { h1b, h2b };
    for (int l = 0; l < 2; l++) {
        fused_gather_bf16<<<GATHER_BLOCKS, 256, 0, stream>>>(
            hin[l], csr_src, ofs, dinv, rdegn, aggGb, meanb, N_NODES);
        layer_fused_kernel<<<GEMM_BLOCKS, 256, 0, stream>>>(
            aggGb, hin[l], meanb,
            Wp + (size_t)(1 + l) * WPM, Wp + (size_t)(3 + l) * WPM, Wp + (size_t)(5 + l) * WPM,
            gcn_b + l * 128, ln_g + l * 128, ln_b + l * 128,
            a_conv + l * 2, a_norm + l * 2, a_act + l * 3,
            hout[l], N_NODES);
    }

    hipMemsetAsync(pooled, 0, (size_t)G_GRAPHS * 128 * sizeof(float), stream);
    pool_sum_kernel<<<(N_NODES + 127) / 128, 256, 0, stream>>>(h1b, h2b, batch, pooled, N_NODES);
    post_gemm_kernel<<<G_GRAPHS, 64, 0, stream>>>(pooled, post_w, post_b, (float*)d_out);
}